// Round 3
// baseline (941.369 us; speedup 1.0000x reference)
//
#include <hip/hip_runtime.h>
#include <hip/hip_bf16.h>

#define BB 64
#define NHEADS 4
#define MM 6
#define RR 24        // NHEADS*MM query rows per batch
#define CC 96        // channels
#define NN 12544     // 112*112 spatial
#define DD 192
#define NC 256       // n-chunk per block
#define NCHUNK 49    // 12544/256
#define QSCALE 0.10206207261596577f  // 96^-0.5

typedef __attribute__((ext_vector_type(8))) short short8;
typedef __attribute__((ext_vector_type(4))) float float4v;

__device__ __forceinline__ float b2f(ushort u) {
    union { float f; unsigned int u32; } v; v.u32 = ((unsigned int)u) << 16; return v.f;
}
__device__ __forceinline__ ushort f2b(float f) {
    union { float f; unsigned int u; } v; v.f = f;
    unsigned int u = v.u;
    unsigned int r = (u + 0x7FFFu + ((u >> 16) & 1u)) >> 16;
    return (ushort)r;
}

// ---------------- kernel A: Q = (z@Wq + bq) * scale ; zero accumulators ----
__global__ __launch_bounds__(256) void kA(const float* __restrict__ z,
                                          const float* __restrict__ Wq,
                                          const float* __restrict__ bq,
                                          float* __restrict__ Q,
                                          float* __restrict__ Oacc,
                                          float* __restrict__ sacc) {
    __shared__ float zl[MM * DD];
    int t = threadIdx.x;
    int b = blockIdx.x;
    for (int i = t; i < MM * DD; i += 256) zl[i] = z[(size_t)b * MM * DD + i];
    for (int i = t; i < RR * CC; i += 256) Oacc[(size_t)b * RR * CC + i] = 0.f;
    if (t < RR) sacc[b * RR + t] = 0.f;
    __syncthreads();
    for (int o = t; o < RR * CC; o += 256) {
        int r = o / CC;
        int ch = o - r * CC;
        int h = r / MM;
        int m = r - h * MM;
        int col = h * CC + ch;
        float acc = bq[col];
        #pragma unroll 4
        for (int k = 0; k < DD; ++k)
            acc += zl[m * DD + k] * Wq[(size_t)k * (NHEADS * CC) + col];
        Q[((size_t)b * RR + r) * CC + ch] = acc * QSCALE;
    }
}

// ---------------- kernel B: fused scores+exp (VALU) and PV (MFMA) ---------
__global__ __launch_bounds__(256) void kB(const float* __restrict__ x,
                                          const float* __restrict__ Q,
                                          float* __restrict__ Oacc,
                                          float* __restrict__ sacc) {
    __shared__ ushort xs[CC * NC];   // bf16 [ch][n ^ ((ch&3)<<4)]  48 KB
    __shared__ ushort es[RR * NC];   // bf16 [r][n ^ ((r&3)<<4)]    12 KB
    int t = threadIdx.x;
    int bidx = blockIdx.x;
    int b = bidx / NCHUNK;
    int chunk = bidx - b * NCHUNK;
    int n0 = chunk * NC;

    // ---- stage x tile: f32 float4 loads, convert to bf16, swizzled store --
    const float* xg = x + (size_t)b * CC * NN + n0;
    #pragma unroll
    for (int i = 0; i < 24; ++i) {
        int c = t + i * 256;          // 0..6143 : 96 rows * 64 chunks of 4
        int ch = c >> 6;
        int n = (c & 63) * 4;
        float4 v = *(const float4*)(xg + (size_t)ch * NN + n);
        ushort4 w;
        w.x = f2b(v.x); w.y = f2b(v.y); w.z = f2b(v.z); w.w = f2b(v.w);
        int nsw = n ^ ((ch & 3) << 4);   // swizzle hits bits 4-5; 4-contig ok
        *(ushort4*)(&xs[ch * NC + nsw]) = w;
    }
    __syncthreads();

    // ---- pass 1: 24 dots per column (thread t owns column n0+t) ----
    float dot[RR];
    #pragma unroll
    for (int r = 0; r < RR; ++r) dot[r] = 0.f;
    const float* __restrict__ Qb = Q + (size_t)b * (RR * CC);
    int tx0 = t, tx1 = t ^ 16, tx2 = t ^ 32, tx3 = t ^ 48;
    for (int cb = 0; cb < CC; cb += 4) {
        float xv0 = b2f(xs[(cb + 0) * NC + tx0]);
        float xv1 = b2f(xs[(cb + 1) * NC + tx1]);
        float xv2 = b2f(xs[(cb + 2) * NC + tx2]);
        float xv3 = b2f(xs[(cb + 3) * NC + tx3]);
        #pragma unroll
        for (int r = 0; r < RR; ++r) {
            float4 q = *(const float4*)(Qb + r * CC + cb);  // wave-uniform -> s_load
            dot[r] += q.x * xv0 + q.y * xv1 + q.z * xv2 + q.w * xv3;
        }
    }

    // ---- exp, write e-tile (bf16), reduce partial softmax denominators ----
    int lane = t & 63;
    #pragma unroll
    for (int r = 0; r < RR; ++r) {
        float d = fminf(fmaxf(dot[r], -30.f), 30.f);
        float e = __expf(d);
        es[r * NC + (t ^ ((r & 3) << 4))] = f2b(e);
        float v = e;
        #pragma unroll
        for (int off = 32; off > 0; off >>= 1) v += __shfl_xor(v, off, 64);
        if (lane == 0) atomicAdd(&sacc[b * RR + r], v);
    }
    __syncthreads();

    // ---- pass 2: O_partial(24x96) += E(24x256) @ X^T(256x96) via MFMA ----
    int w = t >> 6;              // wave 0..3
    int quad = lane >> 4;
    int l15 = lane & 15;
    int rtile = w & 1;           // rows 0-15 / 16-31(8 valid)
    int cbase = (w >> 1) * 3;    // 3 ch-tiles of 16 per wave
    int ar = rtile * 16 + l15;
    if (ar > 23) ar = 23;        // clamp: duplicate row 23 (results discarded)
    int arow = ar * NC;
    int asw = (ar & 3) << 4;
    float4v acc0 = {0.f, 0.f, 0.f, 0.f};
    float4v acc1 = {0.f, 0.f, 0.f, 0.f};
    float4v acc2 = {0.f, 0.f, 0.f, 0.f};
    int ch0 = (cbase + 0) * 16 + l15;
    int ch1 = (cbase + 1) * 16 + l15;
    int ch2 = (cbase + 2) * 16 + l15;
    int sw0 = (ch0 & 3) << 4, sw1 = (ch1 & 3) << 4, sw2 = (ch2 & 3) << 4;
    #pragma unroll
    for (int kk = 0; kk < 8; ++kk) {
        int an = kk * 32 + quad * 8;
        short8 a = *(const short8*)(&es[arow + (an ^ asw)]);
        short8 b0 = *(const short8*)(&xs[ch0 * NC + (an ^ sw0)]);
        short8 b1 = *(const short8*)(&xs[ch1 * NC + (an ^ sw1)]);
        short8 b2 = *(const short8*)(&xs[ch2 * NC + (an ^ sw2)]);
        acc0 = __builtin_amdgcn_mfma_f32_16x16x32_bf16(a, b0, acc0, 0, 0, 0);
        acc1 = __builtin_amdgcn_mfma_f32_16x16x32_bf16(a, b1, acc1, 0, 0, 0);
        acc2 = __builtin_amdgcn_mfma_f32_16x16x32_bf16(a, b2, acc2, 0, 0, 0);
    }
    #pragma unroll
    for (int reg = 0; reg < 4; ++reg) {
        int r = rtile * 16 + quad * 4 + reg;   // C/D: row=quad*4+reg, col=lane&15
        if (r < RR) {
            size_t base = ((size_t)b * RR + r) * CC;
            atomicAdd(&Oacc[base + (cbase + 0) * 16 + l15], acc0[reg]);
            atomicAdd(&Oacc[base + (cbase + 1) * 16 + l15], acc1[reg]);
            atomicAdd(&Oacc[base + (cbase + 2) * 16 + l15], acc2[reg]);
        }
    }
}

// ---------------- kernel C: O /= sum ; out = z + O@Wo + bo ----------------
__global__ __launch_bounds__(256) void kC(const float* __restrict__ z,
                                          const float* __restrict__ Wo,
                                          const float* __restrict__ bo,
                                          const float* __restrict__ Oacc,
                                          const float* __restrict__ sacc,
                                          float* __restrict__ out) {
    __shared__ float ol[RR * CC];
    int t = threadIdx.x;
    int b = blockIdx.x;
    for (int o = t; o < RR * CC; o += 256) {
        int r = o / CC;
        ol[o] = Oacc[(size_t)b * RR * CC + o] / sacc[b * RR + r];
    }
    __syncthreads();
    for (int o = t; o < MM * DD; o += 256) {
        int m = o / DD;
        int d = o - m * DD;
        float acc = bo[d] + z[(size_t)b * MM * DD + o];
        #pragma unroll
        for (int h = 0; h < NHEADS; ++h) {
            const float* orow = &ol[(h * MM + m) * CC];
            const float* wrow = Wo + (size_t)(h * CC) * DD + d;
            #pragma unroll 4
            for (int ch = 0; ch < CC; ++ch)
                acc += orow[ch] * wrow[(size_t)ch * DD];
        }
        out[(size_t)b * MM * DD + o] = acc;
    }
}

extern "C" void kernel_launch(void* const* d_in, const int* in_sizes, int n_in,
                              void* d_out, int out_size, void* d_ws, size_t ws_size,
                              hipStream_t stream) {
    const float* x  = (const float*)d_in[0];
    const float* z  = (const float*)d_in[1];
    const float* Wq = (const float*)d_in[2];
    const float* bq = (const float*)d_in[3];
    const float* Wo = (const float*)d_in[4];
    const float* bo = (const float*)d_in[5];

    float* Q    = (float*)d_ws;                 // 64*24*96 fp32
    float* Oacc = Q + (size_t)BB * RR * CC;     // 64*24*96 fp32
    float* sacc = Oacc + (size_t)BB * RR * CC;  // 64*24    fp32

    kA<<<BB, 256, 0, stream>>>(z, Wq, bq, Q, Oacc, sacc);
    kB<<<BB * NCHUNK, 256, 0, stream>>>(x, Q, Oacc, sacc);
    kC<<<BB, 256, 0, stream>>>(z, Wo, bo, Oacc, sacc, (float*)d_out);
}

// Round 4
// 603.306 us; speedup vs baseline: 1.5604x; 1.5604x over previous
//
#include <hip/hip_runtime.h>

#define BB 64
#define NHEADS 4
#define MM 6
#define RR 24        // NHEADS*MM query rows per batch
#define CC 96        // channels
#define NN 12544     // 112*112 spatial
#define DD 192
#define NC 128       // n per chunk
#define TCH 7        // chunks per block
#define NGRP 14      // chunk groups: 14*7*128 = 12544
#define QSCALE 0.10206207261596577f  // 96^-0.5

typedef __attribute__((ext_vector_type(8))) short short8;
typedef __attribute__((ext_vector_type(4))) float float4v;

__device__ __forceinline__ ushort f2b(float f) {
    union { float f; unsigned int u; } v; v.f = f;
    unsigned int u = v.u;
    unsigned int r = (u + 0x7FFFu + ((u >> 16) & 1u)) >> 16;
    return (ushort)r;
}

// ---- kernel A: Q = (z@Wq + bq)*scale -> bf16 ; zero accumulators ---------
// grid 64*3 blocks, 256 thr. block (b, rg): rows rg*8..rg*8+7
__global__ __launch_bounds__(256) void kA(const float* __restrict__ z,
                                          const float* __restrict__ Wq,
                                          const float* __restrict__ bq,
                                          ushort* __restrict__ Qg,
                                          float* __restrict__ Oacc,
                                          float* __restrict__ sacc) {
    __shared__ float zl[MM * DD];
    int t = threadIdx.x;
    int b = blockIdx.x / 3;
    int rg = blockIdx.x % 3;
    for (int i = t; i < MM * DD; i += 256) zl[i] = z[(size_t)b * MM * DD + i];
    for (int i = t; i < 768; i += 256) Oacc[(size_t)b * RR * CC + rg * 768 + i] = 0.f;
    if (rg == 0 && t < RR) sacc[b * RR + t] = 0.f;
    __syncthreads();
    #pragma unroll
    for (int i = 0; i < 3; ++i) {
        int idx = t + i * 256;            // 0..767 = 8 rows x 96 ch
        int rr = idx / CC;
        int ch = idx - rr * CC;
        int r = rg * 8 + rr;
        int h = r / MM, m = r - h * MM;
        int col = h * CC + ch;
        float acc = bq[col];
        #pragma unroll 4
        for (int k = 0; k < DD; ++k)
            acc += zl[m * DD + k] * Wq[(size_t)k * (NHEADS * CC) + col];
        Qg[((size_t)b * RR + r) * CC + ch] = f2b(acc * QSCALE);
    }
}

// ---- kernel B: full-MFMA fused attention over 7 chunks -------------------
// grid 64*14, 256 thr, 4 blocks/CU.
// xs layout: row ch (stride 128), 16B chunk at phys = (n>>3) ^ (ch&7), elem n&7
// es layout: same swizzle with row r
__global__ __launch_bounds__(256, 4) void kB(const float* __restrict__ x,
                                             const ushort* __restrict__ Qg,
                                             float* __restrict__ Oacc,
                                             float* __restrict__ sacc) {
    __shared__ ushort xs[CC * NC];     // 24576 B
    __shared__ ushort es[32 * NC];     // 8192 B
    __shared__ ushort Qs[32 * 104];    // 6656 B (stride 104 for bank spread)
    __shared__ float sdenL[RR];

    int t = threadIdx.x;
    int b = blockIdx.x / NGRP;
    int grp = blockIdx.x - b * NGRP;
    int w = t >> 6, lane = t & 63, q = lane >> 4, l15 = lane & 15;

    // stage Q (bf16) into Qs; zero pad rows 24..31
    for (int i = t; i < 32 * 104; i += 256) Qs[i] = 0;
    __syncthreads();   // avoid racing zero-fill with the fill below
    for (int i = t; i < RR * CC; i += 256) {
        int r = i / CC, ch = i - r * CC;
        Qs[r * 104 + ch] = Qg[((size_t)b * RR + r) * CC + ch];
    }
    if (t < RR) sdenL[t] = 0.f;

    // pass2 accumulators live across chunks: wave w -> rt2 = w&1, ch-tiles 3*(w>>1)..+2
    int rt2 = w & 1;
    int ct0 = (w >> 1) * 3;
    float4v oacc0 = {0.f,0.f,0.f,0.f}, oacc1 = {0.f,0.f,0.f,0.f}, oacc2 = {0.f,0.f,0.f,0.f};

    for (int c = 0; c < TCH; ++c) {
        int n0 = (grp * TCH + c) * NC;
        // ---- stage x chunk: f32 float4 loads -> bf16 swizzled 8B stores ----
        const float* xg = x + (size_t)b * CC * NN + n0;
        #pragma unroll
        for (int i = 0; i < 12; ++i) {
            int cc = t + i * 256;          // 0..3071: 96 rows x 32 groups of 4
            int ch = cc >> 5;
            int j4 = cc & 31;
            float4 v = *(const float4*)(xg + (size_t)ch * NN + j4 * 4);
            ushort4 wv;
            wv.x = f2b(v.x); wv.y = f2b(v.y); wv.z = f2b(v.z); wv.w = f2b(v.w);
            int phys = (j4 >> 1) ^ (ch & 7);
            *(ushort4*)(&xs[ch * NC + phys * 8 + (j4 & 1) * 4]) = wv;
        }
        __syncthreads();

        // ---- pass 1: S(24x128) = Qs @ xs via MFMA; wave w owns n-tiles 2w,2w+1
        float4v s00 = {0.f,0.f,0.f,0.f}, s01 = {0.f,0.f,0.f,0.f};
        float4v s10 = {0.f,0.f,0.f,0.f}, s11 = {0.f,0.f,0.f,0.f};
        #pragma unroll
        for (int kt = 0; kt < 3; ++kt) {
            short8 bf0, bf1;
            #pragma unroll
            for (int ntj = 0; ntj < 2; ++ntj) {
                int n = (2 * w + ntj) * 16 + l15;
                int chunkL = n >> 3, nin = n & 7;
                short8 bf;
                #pragma unroll
                for (int j = 0; j < 8; ++j) {
                    int R = kt * 32 + q * 8 + j;     // R&7 == j
                    bf[j] = (short)xs[R * NC + ((chunkL ^ j) << 3) + nin];
                }
                if (ntj == 0) bf0 = bf; else bf1 = bf;
            }
            short8 af0 = *(const short8*)(&Qs[(0 * 16 + l15) * 104 + kt * 32 + q * 8]);
            short8 af1 = *(const short8*)(&Qs[(1 * 16 + l15) * 104 + kt * 32 + q * 8]);
            s00 = __builtin_amdgcn_mfma_f32_16x16x32_bf16(af0, bf0, s00, 0, 0, 0);
            s01 = __builtin_amdgcn_mfma_f32_16x16x32_bf16(af0, bf1, s01, 0, 0, 0);
            s10 = __builtin_amdgcn_mfma_f32_16x16x32_bf16(af1, bf0, s10, 0, 0, 0);
            s11 = __builtin_amdgcn_mfma_f32_16x16x32_bf16(af1, bf1, s11, 0, 0, 0);
        }
        // ---- exp -> es (swizzled), accumulate denominators in LDS ----
        #pragma unroll
        for (int rt = 0; rt < 2; ++rt) {
            #pragma unroll
            for (int ntj = 0; ntj < 2; ++ntj) {
                float4v sv = rt == 0 ? (ntj == 0 ? s00 : s01) : (ntj == 0 ? s10 : s11);
                int n = (2 * w + ntj) * 16 + l15;
                int chunkL = n >> 3, nin = n & 7;
                #pragma unroll
                for (int reg = 0; reg < 4; ++reg) {
                    int r = rt * 16 + q * 4 + reg;
                    float e = __expf(fminf(fmaxf(sv[reg], -30.f), 30.f));
                    es[r * NC + (((chunkL ^ (r & 7))) << 3) + nin] = f2b(e);
                    if (r < RR) atomicAdd(&sdenL[r], e);
                }
            }
        }
        __syncthreads();

        // ---- pass 2: O(24x96) += E(24x128) @ X^T via MFMA, reg-accumulated
        #pragma unroll
        for (int kt = 0; kt < 4; ++kt) {
            int kbase = kt * 32 + q * 8;
            int chunkL = kbase >> 3;               // 4*kt + q
            int ar = rt2 * 16 + l15;
            short8 af = *(const short8*)(&es[ar * NC + ((chunkL ^ (ar & 7)) << 3)]);
            int cr0 = (ct0 + 0) * 16 + l15;
            int cr1 = (ct0 + 1) * 16 + l15;
            int cr2 = (ct0 + 2) * 16 + l15;
            short8 b0 = *(const short8*)(&xs[cr0 * NC + ((chunkL ^ (cr0 & 7)) << 3)]);
            short8 b1 = *(const short8*)(&xs[cr1 * NC + ((chunkL ^ (cr1 & 7)) << 3)]);
            short8 b2 = *(const short8*)(&xs[cr2 * NC + ((chunkL ^ (cr2 & 7)) << 3)]);
            oacc0 = __builtin_amdgcn_mfma_f32_16x16x32_bf16(af, b0, oacc0, 0, 0, 0);
            oacc1 = __builtin_amdgcn_mfma_f32_16x16x32_bf16(af, b1, oacc1, 0, 0, 0);
            oacc2 = __builtin_amdgcn_mfma_f32_16x16x32_bf16(af, b2, oacc2, 0, 0, 0);
        }
        __syncthreads();
    }

    // ---- epilogue: denominators + O partial atomics ----
    if (t < RR) atomicAdd(&sacc[b * RR + t], sdenL[t]);
    #pragma unroll
    for (int reg = 0; reg < 4; ++reg) {
        int r = rt2 * 16 + q * 4 + reg;            // C/D: row=quad*4+reg, col=l15
        if (r < RR) {
            size_t base = ((size_t)b * RR + r) * CC + l15;
            atomicAdd(&Oacc[base + (ct0 + 0) * 16], oacc0[reg]);
            atomicAdd(&Oacc[base + (ct0 + 1) * 16], oacc1[reg]);
            atomicAdd(&Oacc[base + (ct0 + 2) * 16], oacc2[reg]);
        }
    }
}

// ---- kernel C: out = z + (O/sden)@Wo + bo --------------------------------
// grid 64*6 blocks, 192 thr. block (b, m); thread owns output col d.
__global__ __launch_bounds__(192) void kC(const float* __restrict__ z,
                                          const float* __restrict__ Wo,
                                          const float* __restrict__ bo,
                                          const float* __restrict__ Oacc,
                                          const float* __restrict__ sacc,
                                          float* __restrict__ out) {
    __shared__ float oh[NHEADS * CC];   // 384
    int t = threadIdx.x;
    int b = blockIdx.x / MM;
    int m = blockIdx.x - b * MM;
    for (int i = t; i < NHEADS * CC; i += 192) {
        int h = i / CC, ch = i - h * CC;
        int r = h * MM + m;
        oh[i] = Oacc[((size_t)b * RR + r) * CC + ch] / sacc[b * RR + r];
    }
    __syncthreads();
    int d = t;
    float acc = bo[d] + z[((size_t)b * MM + m) * DD + d];
    #pragma unroll 8
    for (int k = 0; k < NHEADS * CC; ++k)
        acc += oh[k] * Wo[(size_t)k * DD + d];
    out[((size_t)b * MM + m) * DD + d] = acc;
}

extern "C" void kernel_launch(void* const* d_in, const int* in_sizes, int n_in,
                              void* d_out, int out_size, void* d_ws, size_t ws_size,
                              hipStream_t stream) {
    const float* x  = (const float*)d_in[0];
    const float* z  = (const float*)d_in[1];
    const float* Wq = (const float*)d_in[2];
    const float* bq = (const float*)d_in[3];
    const float* Wo = (const float*)d_in[4];
    const float* bo = (const float*)d_in[5];

    ushort* Qg  = (ushort*)d_ws;                          // 64*24*96 bf16 = 294912 B
    float* Oacc = (float*)((char*)d_ws + 294912);         // 64*24*96 f32  = 589824 B
    float* sacc = (float*)((char*)d_ws + 294912 + 589824);// 64*24    f32

    kA<<<BB * 3, 256, 0, stream>>>(z, Wq, bq, Qg, Oacc, sacc);
    kB<<<BB * NGRP, 256, 0, stream>>>(x, Qg, Oacc, sacc);
    kC<<<BB * MM, 192, 0, stream>>>(z, Wo, bo, Oacc, sacc, (float*)d_out);
}